// Round 8
// baseline (143.820 us; speedup 1.0000x reference)
//
#include <hip/hip_runtime.h>
#include <hip/hip_bf16.h>
#include <math.h>

#define Hd   1024
#define Bsz  4096
#define Kc   3072      // concatenated K (3 x 1024)

typedef unsigned short u16;
typedef __attribute__((ext_vector_type(8))) u16 u16x8;
typedef __attribute__((ext_vector_type(2))) u16 u16x2;
typedef __attribute__((ext_vector_type(4))) float f32x4;
typedef __attribute__((ext_vector_type(8))) short bf16x8;

__device__ inline u16 f2bf(float f) {
    __hip_bfloat16 h = __float2bfloat16(f);
    return *reinterpret_cast<u16*>(&h);
}

__device__ inline float sigm(float x) { return 1.0f / (1.0f + __expf(-x)); }

__device__ inline void gload16(const void* g, const void* s) {
    __builtin_amdgcn_global_load_lds(
        (const __attribute__((address_space(1))) void*)g,
        (__attribute__((address_space(3))) void*)s, 16, 0, 0);
}

#define BAR()   __builtin_amdgcn_s_barrier()
#define VMW0()  asm volatile("s_waitcnt vmcnt(0)" ::: "memory")
#define LGKM0() asm volatile("s_waitcnt lgkmcnt(0)" ::: "memory")
#define PRIO1() __builtin_amdgcn_s_setprio(1)
#define PRIO0() __builtin_amdgcn_s_setprio(0)

// ---------------------------------------------------------------------------
// prep_A: A_cat bf16 [4096][3072], row m' = 4*r + gate  <-  src row gate*1024+r
// Block 0 additionally zeroes the z-row accumulator region of out.
// ---------------------------------------------------------------------------
__global__ __launch_bounds__(256) void prep_A(const float* __restrict__ U11,
                                              const float* __restrict__ U21,
                                              const float* __restrict__ W01,
                                              u16* __restrict__ Ab,
                                              float* __restrict__ out) {
    if (blockIdx.x == 0) {
        float* outz = out + (size_t)2 * Hd * Bsz;
        for (int i = threadIdx.x; i < Bsz; i += 256) outz[i] = 0.0f;
    }
    int t = blockIdx.x * 256 + threadIdx.x;
    int row = t / 384;
    int kc = (t - row * 384) * 8;
    int r = row >> 2, gate = row & 3;
    int sel = kc >> 10;
    int k = kc & 1023;
    const float* src = (sel == 0) ? W01 : ((sel == 1) ? U21 : U11);
    const float4* p = reinterpret_cast<const float4*>(src + (size_t)(gate * Hd + r) * Hd + k);
    float4 v0 = p[0], v1 = p[1];
    u16x8 o;
    o[0] = f2bf(v0.x); o[1] = f2bf(v0.y); o[2] = f2bf(v0.z); o[3] = f2bf(v0.w);
    o[4] = f2bf(v1.x); o[5] = f2bf(v1.y); o[6] = f2bf(v1.z); o[7] = f2bf(v1.w);
    *reinterpret_cast<u16x8*>(Ab + (size_t)row * Kc + kc) = o;
}

// ---------------------------------------------------------------------------
// prep_perm: stable 4-way partition of columns by group g(z,zb).
// Slot order: g3 (z=1,zb=1, K=48 tiles) first, then g2 (0,1), then g1 (1,0).
// g0 (0,0) gets no slot (no GEMM needed). Deterministic (stable scan).
// meta: [0]=Ttot [1]=t3 [2]=t3+t2 [3]=items (=Ttot*32) [8]=work counter (zeroed)
// ---------------------------------------------------------------------------
__global__ __launch_bounds__(1024) void prep_perm(const float* __restrict__ z,
                                                  const float* __restrict__ zb,
                                                  int* __restrict__ n_of_slot,
                                                  int* __restrict__ slot_of_n,
                                                  int* __restrict__ meta) {
    __shared__ int wtot[16][4];
    __shared__ int wbase[16][4];
    __shared__ int gbase[4];
    const int t = threadIdx.x, lane = t & 63, wv = t >> 6;
    int g[4]; int cnt[4] = {0, 0, 0, 0};
    const int n0 = t * 4;
#pragma unroll
    for (int j = 0; j < 4; ++j) {
        float zv = z[n0 + j], zbv = zb[n0 + j];
        int gg = (zv != 0.f) ? (zbv != 0.f ? 3 : 1) : (zbv != 0.f ? 2 : 0);
        g[j] = gg; cnt[gg]++;
    }
    int incl[4];
#pragma unroll
    for (int q = 0; q < 4; ++q) incl[q] = cnt[q];
    for (int off = 1; off < 64; off <<= 1) {
#pragma unroll
        for (int q = 0; q < 4; ++q) {
            int vv = __shfl_up(incl[q], off, 64);
            if (lane >= off) incl[q] += vv;
        }
    }
    if (lane == 63) {
#pragma unroll
        for (int q = 0; q < 4; ++q) wtot[wv][q] = incl[q];
    }
    for (int s = t; s < 4864; s += 1024) n_of_slot[s] = -1;
    __syncthreads();
    if (t == 0) {
        int run[4] = {0, 0, 0, 0};
        for (int ww = 0; ww < 16; ++ww) {
#pragma unroll
            for (int q = 0; q < 4; ++q) { wbase[ww][q] = run[q]; run[q] += wtot[ww][q]; }
        }
        int t3 = (run[3] + 255) >> 8, t2c = (run[2] + 255) >> 8, t1c = (run[1] + 255) >> 8;
        gbase[3] = 0; gbase[2] = t3 << 8; gbase[1] = (t3 + t2c) << 8; gbase[0] = 0;
        int Ttot = t3 + t2c + t1c;
        meta[0] = Ttot; meta[1] = t3; meta[2] = t3 + t2c; meta[3] = Ttot << 5;
        meta[8] = 0;   // persistent-gemm work counter
    }
    __syncthreads();
    int off[4];
#pragma unroll
    for (int q = 0; q < 4; ++q) off[q] = wbase[wv][q] + incl[q] - cnt[q];
#pragma unroll
    for (int j = 0; j < 4; ++j) {
        int gg = g[j];
        int slot = (gg == 0) ? -1 : (gbase[gg] + off[gg]);
        off[gg]++;
        slot_of_n[n0 + j] = slot;
        if (slot >= 0) n_of_slot[slot] = n0 + j;
    }
}

// ---------------------------------------------------------------------------
// prep_B: permuted B_cat bf16 Bp[slot][3072] (transpose + per-column z gating);
// writes only the K-segments the column's group actually reads.
// Fused: z-row partial dot-products accumulated via atomicAdd (all columns).
// ---------------------------------------------------------------------------
__global__ __launch_bounds__(256) void prep_B(const float* __restrict__ hb,
                                              const float* __restrict__ ht,
                                              const float* __restrict__ hh,
                                              const float* __restrict__ z,
                                              const float* __restrict__ zb,
                                              const float* __restrict__ U11,
                                              const float* __restrict__ U21,
                                              const float* __restrict__ W01,
                                              const int* __restrict__ slot_of_n,
                                              u16* __restrict__ Bp,
                                              float* __restrict__ out) {
    __shared__ float tile[64][33];
    __shared__ float red[8][32];
    int n0 = blockIdx.x * 32;
    int kg0 = blockIdx.y * 64;
    int sel = kg0 >> 10;
    int k0 = kg0 & 1023;
    const float* src = (sel == 0) ? hb : ((sel == 1) ? ht : hh);
    const float* wsrc = (sel == 0) ? W01 : ((sel == 1) ? U21 : U11);
    int t = threadIdx.x, tx = t & 31, ty = t >> 5;
#pragma unroll
    for (int j = 0; j < 8; ++j) {
        int kk = ty * 8 + j;
        tile[kk][tx] = src[(size_t)(k0 + kk) * Bsz + n0 + tx];
    }
    __syncthreads();
    {   // bf16 transpose+gate write into permuted slot rows (segment-gated)
        int kp = t & 31, ny = t >> 5;
#pragma unroll
        for (int j = 0; j < 4; ++j) {
            int nl = ny * 4 + j;
            int n = n0 + nl;
            float zv = z[n], zbv = zb[n];
            int gg = (zv != 0.f) ? (zbv != 0.f ? 3 : 1) : (zbv != 0.f ? 2 : 0);
            bool need = (sel == 0) ? (gg != 0) : ((sel == 1) ? ((gg & 1) != 0) : (gg >= 2));
            int slot = slot_of_n[n];
            if (need && slot >= 0) {
                float s = (sel == 0) ? 1.0f : ((sel == 1) ? zv : zbv);
                u16x2 o;
                o[0] = f2bf(tile[kp * 2][nl] * s);
                o[1] = f2bf(tile[kp * 2 + 1][nl] * s);
                *reinterpret_cast<u16x2*>(Bp + (size_t)slot * Kc + kg0 + kp * 2) = o;
            }
        }
    }
    {   // fused z-row partial
        int col = t & 31, seg = t >> 5;
        const float* w = wsrc + (size_t)4096 * 1024 + k0 + seg * 8;
        float p = 0.0f;
#pragma unroll
        for (int j = 0; j < 8; ++j) p += w[j] * tile[seg * 8 + j][col];
        red[seg][col] = p;
        __syncthreads();
        if (seg == 0) {
            float tot = 0.0f;
#pragma unroll
            for (int q = 0; q < 8; ++q) tot += red[q][col];
            int n = n0 + col;
            float sca = (sel == 0) ? 1.0f : ((sel == 1) ? z[n] : zb[n]);
            atomicAdd(out + (size_t)2 * Hd * Bsz + n, tot * sca);
        }
    }
}

// ---------------------------------------------------------------------------
// copy_pass: group-(0,0) columns are pure pass-through (c_new=c, h_new=h);
// also finalizes the z-row (after prep_B's atomics).
// ---------------------------------------------------------------------------
__global__ __launch_bounds__(256) void copy_pass(const float* __restrict__ c_in,
                                                 const float* __restrict__ h_in,
                                                 const float* __restrict__ z,
                                                 const float* __restrict__ zb,
                                                 const float* __restrict__ bias,
                                                 float* __restrict__ out) {
    int i = blockIdx.x * 256 + threadIdx.x;        // 16384 blocks -> Hd*Bsz threads
    if (i < Bsz) {
        float* outz = out + (size_t)2 * Hd * Bsz;
        float s = outz[i] + bias[4096];
        float zh = (s + 1.0f) * 0.5f;
        zh = fminf(fmaxf(zh, 0.0f), 1.0f);
        outz[i] = (zh > 0.5f) ? 1.0f : 0.0f;
    }
    int r = i >> 12, n = i & 4095;
    if (z[n] == 0.f && zb[n] == 0.f) {
        out[(size_t)r * Bsz + n] = h_in[(size_t)r * Bsz + n];
        out[(size_t)Hd * Bsz + (size_t)r * Bsz + n] = c_in[(size_t)r * Bsz + n];
    }
}

// ---------------------------------------------------------------------------
// gemm_fused: persistent work-queue GEMM. Item = (column tile of 256 permuted
// slots) x (mseg of 128 A-rows). Per-group K-extent: g3=48 tiles, g2=32
// (skip kt 16..31), g1=32. 512 thr / 8 waves (2M x 4N), per-wave 64x64 out.
// One barrier + VMW(0)-on-1-tile-aged-loads per K-tile (R7 lesson, simplest
// form). XOR-swizzled LDS (0 conflicts). Group-specialized fused epilogue.
// ---------------------------------------------------------------------------
__global__ __launch_bounds__(512, 2) void gemm_fused(
    const u16* __restrict__ A, const u16* __restrict__ Bp,
    const int* __restrict__ n_of_slot, int* __restrict__ meta,
    const float* __restrict__ c_in, const float* __restrict__ bias,
    float* __restrict__ out) {
    extern __shared__ __align__(16) u16 smem[];
    u16* const As = smem;             // [2][128*64]  32 KB
    u16* const Bs = smem + 16384;     // [2][256*64]  64 KB
    int* const shi = (int*)(smem + 49152);

    const int t = threadIdx.x;
    const int w = t >> 6, l = t & 63;
    const int wm = w >> 2, wn = w & 3;           // 2M x 4N
    const int srow = t >> 3;
    const int sgs  = (t & 7) ^ (srow & 7);
    const int fr = l & 15, fq = l >> 4, fkey = l & 7;

    const int Ttot = meta[0];
    const int t3 = meta[1], t32 = meta[2];
    const int items = meta[3];
    int* ctr = meta + 8;

    for (;;) {
        __syncthreads();                          // item boundary (LDS reuse safe)
        if (t == 0) *shi = atomicAdd(ctr, 1);
        __syncthreads();
        const int item = *shi;
        if (item >= items) break;
        const int tile = item >> 5, mseg = item & 31;
        const int grp = (tile < t3) ? 3 : ((tile < t32) ? 2 : 1);
        const int NTg = (grp == 3) ? 48 : 32;

        const u16* Aitem = A  + (size_t)(mseg * 128 + srow) * Kc + sgs * 8;
        const u16* Bitem = Bp + ((size_t)tile * 256 + srow) * Kc + sgs * 8;

        f32x4 acc[4][4];
#pragma unroll
        for (int i = 0; i < 4; ++i)
#pragma unroll
            for (int j = 0; j < 4; ++j) acc[i][j] = (f32x4){0.f, 0.f, 0.f, 0.f};

        auto ktmap = [&](int kt) { return (grp == 2 && kt >= 16) ? kt + 16 : kt; };
        auto stage = [&](int p, int ktg) {
#pragma unroll
            for (int iss = 0; iss < 2; ++iss)
                gload16(Aitem + (size_t)(iss * 64) * Kc + ktg * 64,
                        As + p * 8192 + (iss * 64 + (w << 3)) * 64);
#pragma unroll
            for (int iss = 0; iss < 4; ++iss)
                gload16(Bitem + (size_t)(iss * 64) * Kc + ktg * 64,
                        Bs + p * 16384 + (iss * 64 + (w << 3)) * 64);
        };

        stage(0, ktmap(0));
        for (int tt = 0; tt < NTg; ++tt) {
            const int p = tt & 1;
            LGKM0(); VMW0(); BAR();
            if (tt + 1 < NTg) stage(p ^ 1, ktmap(tt + 1));
            // compute tile tt from buf p
            bf16x8 aF[4][2], bF[4][2];
#pragma unroll
            for (int mi = 0; mi < 4; ++mi)
#pragma unroll
                for (int ks = 0; ks < 2; ++ks)
                    aF[mi][ks] = *reinterpret_cast<const bf16x8*>(
                        As + p * 8192 + (wm * 64 + mi * 16 + fr) * 64 +
                        ((((ks << 2) + fq) ^ fkey) << 3));
#pragma unroll
            for (int ni = 0; ni < 4; ++ni)
#pragma unroll
                for (int ks = 0; ks < 2; ++ks)
                    bF[ni][ks] = *reinterpret_cast<const bf16x8*>(
                        Bs + p * 16384 + (wn * 64 + ni * 16 + fr) * 64 +
                        ((((ks << 2) + fq) ^ fkey) << 3));
            PRIO1();
#pragma unroll
            for (int mi = 0; mi < 4; ++mi)
#pragma unroll
                for (int ni = 0; ni < 4; ++ni)
#pragma unroll
                    for (int ks = 0; ks < 2; ++ks)
                        acc[mi][ni] = __builtin_amdgcn_mfma_f32_16x16x32_bf16(
                            aF[mi][ks], bF[ni][ks], acc[mi][ni], 0, 0, 0);
            PRIO0();
        }

        // group-specialized fused epilogue
        int nsl[4];
#pragma unroll
        for (int ni = 0; ni < 4; ++ni)
            nsl[ni] = n_of_slot[tile * 256 + wn * 64 + ni * 16 + fr];
#pragma unroll
        for (int mi = 0; mi < 4; ++mi) {
            const int r = mseg * 32 + wm * 16 + mi * 4 + fq;
            const float b0 = bias[r], b1 = bias[Hd + r];
            const float b2 = bias[2 * Hd + r], b3 = bias[3 * Hd + r];
#pragma unroll
            for (int ni = 0; ni < 4; ++ni) {
                const int n = nsl[ni];
                if (n < 0) continue;
                f32x4 a = acc[mi][ni];
                float ig = sigm(a[1] + b1);
                float og = sigm(a[2] + b2);
                float gg = tanhf(a[3] + b3);
                float cn;
                if (grp == 2) {
                    float fg = sigm(a[0] + b0);
                    cn = fg * c_in[(size_t)r * Bsz + n] + ig * gg;
                } else {
                    cn = ig * gg;
                }
                float hn = og * tanhf(cn);
                out[(size_t)r * Bsz + n] = hn;
                out[(size_t)Hd * Bsz + (size_t)r * Bsz + n] = cn;
            }
        }
    }
}

extern "C" void kernel_launch(void* const* d_in, const int* in_sizes, int n_in,
                              void* d_out, int out_size, void* d_ws, size_t ws_size,
                              hipStream_t stream) {
    (void)in_sizes; (void)n_in; (void)out_size; (void)ws_size;
    const float* c    = (const float*)d_in[0];
    const float* hb   = (const float*)d_in[1];
    const float* h    = (const float*)d_in[2];
    const float* ht   = (const float*)d_in[3];
    const float* z    = (const float*)d_in[4];
    const float* zb   = (const float*)d_in[5];
    const float* U11  = (const float*)d_in[6];
    const float* U21  = (const float*)d_in[7];
    const float* W01  = (const float*)d_in[8];
    const float* bias = (const float*)d_in[9];
    float* out = (float*)d_out;

    char* wsb = (char*)d_ws;
    u16* Ab        = (u16*)wsb;                                  // 25.17 MB
    u16* Bp        = (u16*)(wsb + (size_t)25165824);             // 29.88 MB (4864 slots)
    int* n_of_slot = (int*)(wsb + (size_t)55050240);             // 19.5 KB
    int* slot_of_n = (int*)(wsb + (size_t)55069696);             // 16 KB
    int* meta      = (int*)(wsb + (size_t)55086080);             // 64 B

    hipFuncSetAttribute(reinterpret_cast<const void*>(gemm_fused),
                        hipFuncAttributeMaxDynamicSharedMemorySize, 98432);

    prep_perm<<<1, 1024, 0, stream>>>(z, zb, n_of_slot, slot_of_n, meta);
    prep_A<<<6144, 256, 0, stream>>>(U11, U21, W01, Ab, out);
    prep_B<<<dim3(128, 48), 256, 0, stream>>>(hb, ht, h, z, zb, U11, U21, W01,
                                              slot_of_n, Bp, out);
    copy_pass<<<16384, 256, 0, stream>>>(c, h, z, zb, bias, out);
    gemm_fused<<<256, 512, 98432, stream>>>(Ab, Bp, n_of_slot, meta, c, bias, out);
}

// Round 9
// 135.591 us; speedup vs baseline: 1.0607x; 1.0607x over previous
//
#include <hip/hip_runtime.h>
#include <hip/hip_bf16.h>
#include <math.h>

#define Hd   1024
#define Bsz  4096
#define Kc   3072      // concatenated K (3 x 1024)

typedef unsigned short u16;
typedef __attribute__((ext_vector_type(8))) u16 u16x8;
typedef __attribute__((ext_vector_type(2))) u16 u16x2;
typedef __attribute__((ext_vector_type(4))) float f32x4;
typedef __attribute__((ext_vector_type(8))) short bf16x8;

__device__ inline u16 f2bf(float f) {
    __hip_bfloat16 h = __float2bfloat16(f);
    return *reinterpret_cast<u16*>(&h);
}

__device__ inline float sigm(float x) { return 1.0f / (1.0f + __expf(-x)); }

__device__ inline void gload16(const void* g, const void* s) {
    __builtin_amdgcn_global_load_lds(
        (const __attribute__((address_space(1))) void*)g,
        (__attribute__((address_space(3))) void*)s, 16, 0, 0);
}

#define BAR()   __builtin_amdgcn_s_barrier()
#define VMW(n)  asm volatile("s_waitcnt vmcnt(" #n ")" ::: "memory")
#define PRIO1() __builtin_amdgcn_s_setprio(1)
#define PRIO0() __builtin_amdgcn_s_setprio(0)

// ---------------------------------------------------------------------------
// prep_A: A_cat bf16 [4096][3072], row m' = 4*r + gate  <-  src row gate*1024+r
// Block 0 additionally zeroes the z-row accumulator region of out.
// ---------------------------------------------------------------------------
__global__ __launch_bounds__(256) void prep_A(const float* __restrict__ U11,
                                              const float* __restrict__ U21,
                                              const float* __restrict__ W01,
                                              u16* __restrict__ Ab,
                                              float* __restrict__ out) {
    if (blockIdx.x == 0) {
        float* outz = out + (size_t)2 * Hd * Bsz;
        for (int i = threadIdx.x; i < Bsz; i += 256) outz[i] = 0.0f;
    }
    int t = blockIdx.x * 256 + threadIdx.x;
    int row = t / 384;
    int kc = (t - row * 384) * 8;
    int r = row >> 2, gate = row & 3;
    int sel = kc >> 10;
    int k = kc & 1023;
    const float* src = (sel == 0) ? W01 : ((sel == 1) ? U21 : U11);
    const float4* p = reinterpret_cast<const float4*>(src + (size_t)(gate * Hd + r) * Hd + k);
    float4 v0 = p[0], v1 = p[1];
    u16x8 o;
    o[0] = f2bf(v0.x); o[1] = f2bf(v0.y); o[2] = f2bf(v0.z); o[3] = f2bf(v0.w);
    o[4] = f2bf(v1.x); o[5] = f2bf(v1.y); o[6] = f2bf(v1.z); o[7] = f2bf(v1.w);
    *reinterpret_cast<u16x8*>(Ab + (size_t)row * Kc + kc) = o;
}

// ---------------------------------------------------------------------------
// prep_perm: stable 4-way partition of columns by group g(z,zb).
// Slot order: g3 (z=1,zb=1, K=48 tiles) first, then g2 (0,1), then g1 (1,0).
// g0 (0,0) gets no slot. meta: [0]=Ttot [1]=t3 [2]=t3+t2
// ---------------------------------------------------------------------------
__global__ __launch_bounds__(1024) void prep_perm(const float* __restrict__ z,
                                                  const float* __restrict__ zb,
                                                  int* __restrict__ n_of_slot,
                                                  int* __restrict__ slot_of_n,
                                                  int* __restrict__ meta) {
    __shared__ int wtot[16][4];
    __shared__ int wbase[16][4];
    __shared__ int gbase[4];
    const int t = threadIdx.x, lane = t & 63, wv = t >> 6;
    int g[4]; int cnt[4] = {0, 0, 0, 0};
    const int n0 = t * 4;
#pragma unroll
    for (int j = 0; j < 4; ++j) {
        float zv = z[n0 + j], zbv = zb[n0 + j];
        int gg = (zv != 0.f) ? (zbv != 0.f ? 3 : 1) : (zbv != 0.f ? 2 : 0);
        g[j] = gg; cnt[gg]++;
    }
    int incl[4];
#pragma unroll
    for (int q = 0; q < 4; ++q) incl[q] = cnt[q];
    for (int off = 1; off < 64; off <<= 1) {
#pragma unroll
        for (int q = 0; q < 4; ++q) {
            int vv = __shfl_up(incl[q], off, 64);
            if (lane >= off) incl[q] += vv;
        }
    }
    if (lane == 63) {
#pragma unroll
        for (int q = 0; q < 4; ++q) wtot[wv][q] = incl[q];
    }
    for (int s = t; s < 4864; s += 1024) n_of_slot[s] = -1;
    __syncthreads();
    if (t == 0) {
        int run[4] = {0, 0, 0, 0};
        for (int ww = 0; ww < 16; ++ww) {
#pragma unroll
            for (int q = 0; q < 4; ++q) { wbase[ww][q] = run[q]; run[q] += wtot[ww][q]; }
        }
        int t3 = (run[3] + 255) >> 8, t2c = (run[2] + 255) >> 8, t1c = (run[1] + 255) >> 8;
        gbase[3] = 0; gbase[2] = t3 << 8; gbase[1] = (t3 + t2c) << 8; gbase[0] = 0;
        int Ttot = t3 + t2c + t1c;
        meta[0] = Ttot; meta[1] = t3; meta[2] = t3 + t2c;
    }
    __syncthreads();
    int off[4];
#pragma unroll
    for (int q = 0; q < 4; ++q) off[q] = wbase[wv][q] + incl[q] - cnt[q];
#pragma unroll
    for (int j = 0; j < 4; ++j) {
        int gg = g[j];
        int slot = (gg == 0) ? -1 : (gbase[gg] + off[gg]);
        off[gg]++;
        slot_of_n[n0 + j] = slot;
        if (slot >= 0) n_of_slot[slot] = n0 + j;
    }
}

// ---------------------------------------------------------------------------
// prep_B: permuted B_cat bf16 Bp[slot][3072] (transpose + per-column z gating);
// writes only the K-segments the column's group actually reads.
// Fused: z-row partial dot-products accumulated via atomicAdd (all columns).
// ---------------------------------------------------------------------------
__global__ __launch_bounds__(256) void prep_B(const float* __restrict__ hb,
                                              const float* __restrict__ ht,
                                              const float* __restrict__ hh,
                                              const float* __restrict__ z,
                                              const float* __restrict__ zb,
                                              const float* __restrict__ U11,
                                              const float* __restrict__ U21,
                                              const float* __restrict__ W01,
                                              const int* __restrict__ slot_of_n,
                                              u16* __restrict__ Bp,
                                              float* __restrict__ out) {
    __shared__ float tile[64][33];
    __shared__ float red[8][32];
    int n0 = blockIdx.x * 32;
    int kg0 = blockIdx.y * 64;
    int sel = kg0 >> 10;
    int k0 = kg0 & 1023;
    const float* src = (sel == 0) ? hb : ((sel == 1) ? ht : hh);
    const float* wsrc = (sel == 0) ? W01 : ((sel == 1) ? U21 : U11);
    int t = threadIdx.x, tx = t & 31, ty = t >> 5;
#pragma unroll
    for (int j = 0; j < 8; ++j) {
        int kk = ty * 8 + j;
        tile[kk][tx] = src[(size_t)(k0 + kk) * Bsz + n0 + tx];
    }
    __syncthreads();
    {   // bf16 transpose+gate write into permuted slot rows (segment-gated)
        int kp = t & 31, ny = t >> 5;
#pragma unroll
        for (int j = 0; j < 4; ++j) {
            int nl = ny * 4 + j;
            int n = n0 + nl;
            float zv = z[n], zbv = zb[n];
            int gg = (zv != 0.f) ? (zbv != 0.f ? 3 : 1) : (zbv != 0.f ? 2 : 0);
            bool need = (sel == 0) ? (gg != 0) : ((sel == 1) ? ((gg & 1) != 0) : (gg >= 2));
            int slot = slot_of_n[n];
            if (need && slot >= 0) {
                float s = (sel == 0) ? 1.0f : ((sel == 1) ? zv : zbv);
                u16x2 o;
                o[0] = f2bf(tile[kp * 2][nl] * s);
                o[1] = f2bf(tile[kp * 2 + 1][nl] * s);
                *reinterpret_cast<u16x2*>(Bp + (size_t)slot * Kc + kg0 + kp * 2) = o;
            }
        }
    }
    {   // fused z-row partial
        int col = t & 31, seg = t >> 5;
        const float* w = wsrc + (size_t)4096 * 1024 + k0 + seg * 8;
        float p = 0.0f;
#pragma unroll
        for (int j = 0; j < 8; ++j) p += w[j] * tile[seg * 8 + j][col];
        red[seg][col] = p;
        __syncthreads();
        if (seg == 0) {
            float tot = 0.0f;
#pragma unroll
            for (int q = 0; q < 8; ++q) tot += red[q][col];
            int n = n0 + col;
            float sca = (sel == 0) ? 1.0f : ((sel == 1) ? z[n] : zb[n]);
            atomicAdd(out + (size_t)2 * Hd * Bsz + n, tot * sca);
        }
    }
}

// ---------------------------------------------------------------------------
// copy_pass: group-(0,0) columns are pure pass-through (c_new=c, h_new=h);
// also finalizes the z-row (after prep_B's atomics).
// ---------------------------------------------------------------------------
__global__ __launch_bounds__(256) void copy_pass(const float* __restrict__ c_in,
                                                 const float* __restrict__ h_in,
                                                 const float* __restrict__ z,
                                                 const float* __restrict__ zb,
                                                 const float* __restrict__ bias,
                                                 float* __restrict__ out) {
    int i = blockIdx.x * 256 + threadIdx.x;
    if (i < Bsz) {
        float* outz = out + (size_t)2 * Hd * Bsz;
        float s = outz[i] + bias[4096];
        float zh = (s + 1.0f) * 0.5f;
        zh = fminf(fmaxf(zh, 0.0f), 1.0f);
        outz[i] = (zh > 0.5f) ? 1.0f : 0.0f;
    }
    int r = i >> 12, n = i & 4095;
    if (z[n] == 0.f && zb[n] == 0.f) {
        out[(size_t)r * Bsz + n] = h_in[(size_t)r * Bsz + n];
        out[(size_t)Hd * Bsz + (size_t)r * Bsz + n] = c_in[(size_t)r * Bsz + n];
    }
}

// ---------------------------------------------------------------------------
// gemm_fused: static item grid, item = tile(19,major)*32 + mseg. Per item:
// BM=128 (mseg rows) x BN=256 (permuted slots), BK=64. K-extent per group:
// g3=48 tiles, g2=32 (kt 0..15,32..47 via ktmap), g1=32. 8 waves (2M x 4N),
// per-wave 64x64 out, acc[4][4]. R7's verified 4-phase counted-vmcnt ledger:
//   entry invariant: outstanding = {A1(1), B1(2)} = 3
//   ph0: read A0,B0 frags; stage A0' (1);  VMW(3)->A1 done; BAR; MFMA(0,0)
//   ph1: read A1 frags;    stage B0' (2);  VMW(3)->B1 done; BAR; MFMA(1,0)
//   ph2: read B1 frags;    stage A1' (1);                   BAR; MFMA(1,1)
//   ph3: (no reads)        stage B1' (2);  VMW(3)->A0',B0'; BAR; MFMA(0,1)
// XOR-swizzled LDS (0 conflicts). Group-specialized fused epilogue.
// Tile-major item order => long g3 items dispatch first (LPT balance).
// ---------------------------------------------------------------------------
__global__ __launch_bounds__(512, 2) void gemm_fused(
    const u16* __restrict__ A, const u16* __restrict__ Bp,
    const int* __restrict__ n_of_slot, const int* __restrict__ meta,
    const float* __restrict__ c_in, const float* __restrict__ bias,
    float* __restrict__ out) {
    extern __shared__ __align__(16) u16 smem[];
    u16* const As = smem;             // [2][128][64]  32 KB
    u16* const Bs = smem + 16384;     // [2][256][64]  64 KB

    const int Ttot = meta[0], t3 = meta[1], t32 = meta[2];
    const int item = blockIdx.x;
    const int tile = item >> 5, mseg = item & 31;
    if (tile >= Ttot) return;
    const int grp = (tile < t3) ? 3 : ((tile < t32) ? 2 : 1);
    const int NTg = (grp == 3) ? 48 : 32;
    const bool skipmid = (grp == 2);

    const int t = threadIdx.x;
    const int w = t >> 6, l = t & 63;
    const int wr = w >> 2, wc = w & 3;
    const int srow = t >> 3;
    const int sgs  = (t & 7) ^ (srow & 7);
    const int fr = l & 15, fq = l >> 4, fkey = l & 7;

    const u16* gA = A  + (size_t)(mseg * 128 + srow) * Kc + sgs * 8;
    const u16* gB = Bp + ((size_t)tile * 256 + srow) * Kc + sgs * 8;

    f32x4 acc[4][4];
#pragma unroll
    for (int i = 0; i < 4; ++i)
#pragma unroll
        for (int j = 0; j < 4; ++j) acc[i][j] = (f32x4){0.f, 0.f, 0.f, 0.f};

    auto ktmap = [&](int kt) { return (skipmid && kt >= 16) ? kt + 16 : kt; };
    auto stageA = [&](int buf, int mh, int kt) {           // 1 issue (64 rows)
        const int ktg = ktmap(kt);
        gload16(gA + (size_t)(mh * 64) * Kc + ktg * 64,
                As + buf * 8192 + (mh * 64 + (w << 3)) * 64);
    };
    auto stageB = [&](int buf, int nh, int kt) {           // 2 issues (128 rows)
        const int ktg = ktmap(kt);
#pragma unroll
        for (int iss = 0; iss < 2; ++iss)
            gload16(gB + (size_t)(nh * 128 + iss * 64) * Kc + ktg * 64,
                    Bs + buf * 16384 + (nh * 128 + iss * 64 + (w << 3)) * 64);
    };

    bf16x8 aF[2][2][2];   // [mh][miL][ks]
    bf16x8 bF[2][2][2];   // [nh][niL][ks]

    auto readA = [&](int buf, int mh, int miL, int ks) -> bf16x8 {
        int row = mh * 64 + wr * 32 + miL * 16 + fr;
        int g = ((ks << 2) + fq) ^ fkey;
        return *reinterpret_cast<const bf16x8*>(As + buf * 8192 + row * 64 + g * 8);
    };
    auto readB = [&](int buf, int nh, int niL, int ks) -> bf16x8 {
        int row = nh * 128 + wc * 32 + niL * 16 + fr;
        int g = ((ks << 2) + fq) ^ fkey;
        return *reinterpret_cast<const bf16x8*>(Bs + buf * 16384 + row * 64 + g * 8);
    };

#define MFMAQ(mh, nh)                                                         \
    PRIO1();                                                                  \
    _Pragma("unroll")                                                         \
    for (int miL = 0; miL < 2; ++miL)                                         \
        _Pragma("unroll")                                                     \
        for (int niL = 0; niL < 2; ++niL)                                     \
            _Pragma("unroll")                                                 \
            for (int ks = 0; ks < 2; ++ks)                                    \
                acc[(mh)*2 + miL][(nh)*2 + niL] =                             \
                    __builtin_amdgcn_mfma_f32_16x16x32_bf16(                  \
                        aF[mh][miL][ks], bF[nh][niL][ks],                     \
                        acc[(mh)*2 + miL][(nh)*2 + niL], 0, 0, 0);            \
    PRIO0()

    // prologue: stage tile0 A0(1),B0(2),A1(1),B1(2); complete A0,B0 -> VMW(3)
    stageA(0, 0, 0); stageB(0, 0, 0); stageA(0, 1, 0); stageB(0, 1, 0);
    VMW(3); BAR();

    for (int T = 0; T < NTg; ++T) {
        const int p = T & 1, q2 = p ^ 1;
        const bool more = (T + 1 < NTg);
        // ph0: reads A0,B0[T]; stage A0[T+1]; guard A1[T]
#pragma unroll
        for (int miL = 0; miL < 2; ++miL) {
            aF[0][miL][0] = readA(p, 0, miL, 0); aF[0][miL][1] = readA(p, 0, miL, 1);
        }
#pragma unroll
        for (int niL = 0; niL < 2; ++niL) {
            bF[0][niL][0] = readB(p, 0, niL, 0); bF[0][niL][1] = readB(p, 0, niL, 1);
        }
        if (more) { stageA(q2, 0, T + 1); VMW(3); } else { VMW(2); }
        BAR();
        MFMAQ(0, 0);
        // ph1: reads A1[T]; stage B0[T+1]; guard B1[T]
#pragma unroll
        for (int miL = 0; miL < 2; ++miL) {
            aF[1][miL][0] = readA(p, 1, miL, 0); aF[1][miL][1] = readA(p, 1, miL, 1);
        }
        if (more) { stageB(q2, 0, T + 1); VMW(3); } else { VMW(0); }
        BAR();
        MFMAQ(1, 0);
        // ph2: reads B1[T]; stage A1[T+1]
#pragma unroll
        for (int niL = 0; niL < 2; ++niL) {
            bF[1][niL][0] = readB(p, 1, niL, 0); bF[1][niL][1] = readB(p, 1, niL, 1);
        }
        if (more) stageA(q2, 1, T + 1);
        BAR();
        MFMAQ(1, 1);
        // ph3: no reads; stage B1[T+1]; guard A0,B0[T+1]
        if (more) { stageB(q2, 1, T + 1); VMW(3); }
        BAR();
        MFMAQ(0, 1);
    }

    // group-specialized fused epilogue: reg j of acc = gate j of unit u
    int nsl[4];
#pragma unroll
    for (int bj = 0; bj < 4; ++bj) {
        int slot = tile * 256 + (bj >> 1) * 128 + wc * 32 + (bj & 1) * 16 + fr;
        nsl[bj] = n_of_slot[slot];
    }
#pragma unroll
    for (int ai = 0; ai < 4; ++ai) {
        const int u = mseg * 32 + (ai >> 1) * 16 + wr * 8 + (ai & 1) * 4 + fq;
        const float b0 = bias[u], b1 = bias[Hd + u];
        const float b2 = bias[2 * Hd + u], b3 = bias[3 * Hd + u];
#pragma unroll
        for (int bj = 0; bj < 4; ++bj) {
            const int n = nsl[bj];
            if (n < 0) continue;
            f32x4 a = acc[ai][bj];
            float ig = sigm(a[1] + b1);
            float og = sigm(a[2] + b2);
            float gg = tanhf(a[3] + b3);
            float cn;
            if (grp == 2) {
                float fg = sigm(a[0] + b0);
                cn = fg * c_in[(size_t)u * Bsz + n] + ig * gg;
            } else {
                cn = ig * gg;
            }
            float hn = og * tanhf(cn);
            out[(size_t)u * Bsz + n] = hn;
            out[(size_t)Hd * Bsz + (size_t)u * Bsz + n] = cn;
        }
    }
#undef MFMAQ
}

extern "C" void kernel_launch(void* const* d_in, const int* in_sizes, int n_in,
                              void* d_out, int out_size, void* d_ws, size_t ws_size,
                              hipStream_t stream) {
    (void)in_sizes; (void)n_in; (void)out_size; (void)ws_size;
    const float* c    = (const float*)d_in[0];
    const float* hb   = (const float*)d_in[1];
    const float* h    = (const float*)d_in[2];
    const float* ht   = (const float*)d_in[3];
    const float* z    = (const float*)d_in[4];
    const float* zb   = (const float*)d_in[5];
    const float* U11  = (const float*)d_in[6];
    const float* U21  = (const float*)d_in[7];
    const float* W01  = (const float*)d_in[8];
    const float* bias = (const float*)d_in[9];
    float* out = (float*)d_out;

    char* wsb = (char*)d_ws;
    u16* Ab        = (u16*)wsb;                                  // 25.17 MB
    u16* Bp        = (u16*)(wsb + (size_t)25165824);             // 29.88 MB (4864 slots)
    int* n_of_slot = (int*)(wsb + (size_t)55050240);             // 19.5 KB
    int* slot_of_n = (int*)(wsb + (size_t)55069696);             // 16 KB
    int* meta      = (int*)(wsb + (size_t)55086080);             // 64 B

    hipFuncSetAttribute(reinterpret_cast<const void*>(gemm_fused),
                        hipFuncAttributeMaxDynamicSharedMemorySize, 98304);

    prep_perm<<<1, 1024, 0, stream>>>(z, zb, n_of_slot, slot_of_n, meta);
    prep_A<<<6144, 256, 0, stream>>>(U11, U21, W01, Ab, out);
    prep_B<<<dim3(128, 48), 256, 0, stream>>>(hb, ht, h, z, zb, U11, U21, W01,
                                              slot_of_n, Bp, out);
    copy_pass<<<16384, 256, 0, stream>>>(c, h, z, zb, bias, out);
    gemm_fused<<<608, 512, 98304, stream>>>(Ab, Bp, n_of_slot, meta, c, bias, out);
}

// Round 10
// 124.269 us; speedup vs baseline: 1.1573x; 1.0911x over previous
//
#include <hip/hip_runtime.h>
#include <hip/hip_bf16.h>
#include <math.h>

#define Hd   1024
#define Bsz  4096
#define Kc   3072      // concatenated K (3 x 1024)
#define NT   48        // K-tiles of 64

typedef unsigned short u16;
typedef __attribute__((ext_vector_type(8))) u16 u16x8;
typedef __attribute__((ext_vector_type(2))) u16 u16x2;
typedef __attribute__((ext_vector_type(4))) float f32x4;
typedef __attribute__((ext_vector_type(8))) short bf16x8;

__device__ inline u16 f2bf(float f) {
    __hip_bfloat16 h = __float2bfloat16(f);
    return *reinterpret_cast<u16*>(&h);
}

__device__ inline float sigm(float x) { return 1.0f / (1.0f + __expf(-x)); }

__device__ inline void gload16(const void* g, const void* s) {
    __builtin_amdgcn_global_load_lds(
        (const __attribute__((address_space(1))) void*)g,
        (__attribute__((address_space(3))) void*)s, 16, 0, 0);
}

#define BAR()   __builtin_amdgcn_s_barrier()
#define VMW(n)  asm volatile("s_waitcnt vmcnt(" #n ")" ::: "memory")
#define PRIO1() __builtin_amdgcn_s_setprio(1)
#define PRIO0() __builtin_amdgcn_s_setprio(0)

// ---------------------------------------------------------------------------
// prep_A: A_cat bf16 [4096][3072], row m' = 4*r + gate  <-  src row gate*1024+r
// Block 0 additionally zeroes the z-row accumulator region of out.
// ---------------------------------------------------------------------------
__global__ __launch_bounds__(256) void prep_A(const float* __restrict__ U11,
                                              const float* __restrict__ U21,
                                              const float* __restrict__ W01,
                                              u16* __restrict__ Ab,
                                              float* __restrict__ out) {
    if (blockIdx.x == 0) {
        float* outz = out + (size_t)2 * Hd * Bsz;
        for (int i = threadIdx.x; i < Bsz; i += 256) outz[i] = 0.0f;
    }
    int t = blockIdx.x * 256 + threadIdx.x;
    int row = t / 384;
    int kc = (t - row * 384) * 8;
    int r = row >> 2, gate = row & 3;
    int sel = kc >> 10;
    int k = kc & 1023;
    const float* src = (sel == 0) ? W01 : ((sel == 1) ? U21 : U11);
    const float4* p = reinterpret_cast<const float4*>(src + (size_t)(gate * Hd + r) * Hd + k);
    float4 v0 = p[0], v1 = p[1];
    u16x8 o;
    o[0] = f2bf(v0.x); o[1] = f2bf(v0.y); o[2] = f2bf(v0.z); o[3] = f2bf(v0.w);
    o[4] = f2bf(v1.x); o[5] = f2bf(v1.y); o[6] = f2bf(v1.z); o[7] = f2bf(v1.w);
    *reinterpret_cast<u16x8*>(Ab + (size_t)row * Kc + kc) = o;
}

// ---------------------------------------------------------------------------
// prep_B: B_catT bf16 [4096(n)][3072(k')]  (transpose + per-column z gating)
// Fused: z-row partial dot-products (w_row4096 . src) accumulated via atomicAdd.
// ---------------------------------------------------------------------------
__global__ __launch_bounds__(256) void prep_B(const float* __restrict__ hb,
                                              const float* __restrict__ ht,
                                              const float* __restrict__ hh,
                                              const float* __restrict__ z,
                                              const float* __restrict__ zb,
                                              const float* __restrict__ U11,
                                              const float* __restrict__ U21,
                                              const float* __restrict__ W01,
                                              u16* __restrict__ Bb,
                                              float* __restrict__ out) {
    __shared__ float tile[64][33];
    __shared__ float red[8][32];
    int n0 = blockIdx.x * 32;
    int kg0 = blockIdx.y * 64;
    int sel = kg0 >> 10;
    int k0 = kg0 & 1023;
    const float* src = (sel == 0) ? hb : ((sel == 1) ? ht : hh);
    const float* wsrc = (sel == 0) ? W01 : ((sel == 1) ? U21 : U11);
    int t = threadIdx.x, tx = t & 31, ty = t >> 5;
#pragma unroll
    for (int j = 0; j < 8; ++j) {
        int kk = ty * 8 + j;
        tile[kk][tx] = src[(size_t)(k0 + kk) * Bsz + n0 + tx];
    }
    __syncthreads();
    {   // bf16 transpose+gate write
        int kp = t & 31, ny = t >> 5;
#pragma unroll
        for (int j = 0; j < 4; ++j) {
            int nl = ny * 4 + j;
            int n = n0 + nl;
            float s = (sel == 0) ? 1.0f : ((sel == 1) ? z[n] : zb[n]);
            u16x2 o;
            o[0] = f2bf(tile[kp * 2][nl] * s);
            o[1] = f2bf(tile[kp * 2 + 1][nl] * s);
            *reinterpret_cast<u16x2*>(Bb + (size_t)n * Kc + kg0 + kp * 2) = o;
        }
    }
    {   // fused z-row partial
        int col = t & 31, seg = t >> 5;
        const float* w = wsrc + (size_t)4096 * 1024 + k0 + seg * 8;
        float p = 0.0f;
#pragma unroll
        for (int j = 0; j < 8; ++j) p += w[j] * tile[seg * 8 + j][col];
        red[seg][col] = p;
        __syncthreads();
        if (seg == 0) {
            float tot = 0.0f;
#pragma unroll
            for (int q = 0; q < 8; ++q) tot += red[q][col];
            int n = n0 + col;
            float sca = (sel == 0) ? 1.0f : ((sel == 1) ? z[n] : zb[n]);
            atomicAdd(out + (size_t)2 * Hd * Bsz + n, tot * sca);
        }
    }
}

// ---------------------------------------------------------------------------
// gemm_fused: 256x256 tile, BK=64, 8 waves, 16x16x32 MFMA, XOR-swizzled LDS.
// R7 structure with THREE phases per K-tile (was 4): the read-free ph3 is
// merged into ph2, whose MFMA burst becomes q11+q01 (32 MFMA). 3 barriers
// per tile instead of 4. Counted VMW(3) guards, verified ledger:
//   entry invariant: outstanding = {A1[T](1), B1[T](2)} = 3
//   ph0: read A0,B0[T](12); stage A0[T+1](1); VMW(3)->A1[T];   BAR; MFMA q00
//   ph1: read A1[T](8);     stage B0[T+1](2); VMW(3)->B1[T];   BAR; MFMA q10
//   ph2: read B1[T](4);     stage A1,B1[T+1](3); VMW(3)->A0,B0[T+1];
//                                                              BAR; MFMA q11,q01
// Every guarded load >=1 long phase (~1700cyc) old; never drains mid-loop.
// Fused LSTM epilogue; bm==0 blocks finalize the z-row.
// ---------------------------------------------------------------------------
__global__ __launch_bounds__(512, 2) void gemm_fused(
    const u16* __restrict__ A, const u16* __restrict__ Bm,
    const float* __restrict__ c_in, const float* __restrict__ h_in,
    const float* __restrict__ z, const float* __restrict__ zb,
    const float* __restrict__ bias, float* __restrict__ out) {
    extern __shared__ __align__(16) u16 smem[];
    u16* const AsB = smem;            // [2buf][256][64] = 64 KB
    u16* const BsB = smem + 32768;    // [2buf][256][64] = 64 KB

    const int t = threadIdx.x;
    const int w = t >> 6, l = t & 63;
    const int wm = w >> 2, wn = w & 3;

    const int orig = blockIdx.x;                  // 256 wgs, bijective XCD swizzle
    const int wg = ((orig & 7) << 5) | (orig >> 3);
    const int bm = wg >> 4, bn = wg & 15;

    const int srow = t >> 3;                      // staging row within an issue
    const int sgs  = (t & 7) ^ (srow & 7);        // pre-swizzled source granule
    const int fr = l & 15, fq = l >> 4, fkey = l & 7;

    f32x4 acc[8][4];
#pragma unroll
    for (int i = 0; i < 8; ++i)
#pragma unroll
        for (int j = 0; j < 4; ++j) acc[i][j] = (f32x4){0.f, 0.f, 0.f, 0.f};

    const u16* gA = A  + (size_t)(bm * 256 + srow) * Kc + sgs * 8;
    const u16* gB = Bm + (size_t)(bn * 256 + srow) * Kc + sgs * 8;

    auto stageA = [&](int buf, int half, int kt) {
#pragma unroll
        for (int iss = 0; iss < 2; ++iss) {
            const u16* g = gA + (size_t)(half * 128 + iss * 64) * Kc + kt * 64;
            const u16* d = AsB + buf * 16384 + (half * 128 + iss * 64 + (w << 3)) * 64;
            gload16(g, d);
        }
    };
    auto stageB = [&](int buf, int half, int kt) {
#pragma unroll
        for (int iss = 0; iss < 2; ++iss) {
            const u16* g = gB + (size_t)(half * 128 + iss * 64) * Kc + kt * 64;
            const u16* d = BsB + buf * 16384 + (half * 128 + iss * 64 + (w << 3)) * 64;
            gload16(g, d);
        }
    };

    bf16x8 aF[2][4][2];   // [mh][miL][ks]
    bf16x8 bF[2][2][2];   // [nh][niL][ks]

    auto readA = [&](int buf, int mh, int miL, int ks) -> bf16x8 {
        int r = mh * 128 + wm * 64 + miL * 16 + fr;
        int g = ((ks << 2) + fq) ^ fkey;
        return *reinterpret_cast<const bf16x8*>(AsB + buf * 16384 + r * 64 + g * 8);
    };
    auto readB = [&](int buf, int nh, int niL, int ks) -> bf16x8 {
        int r = nh * 128 + wn * 32 + niL * 16 + fr;
        int g = ((ks << 2) + fq) ^ fkey;
        return *reinterpret_cast<const bf16x8*>(BsB + buf * 16384 + r * 64 + g * 8);
    };

#define MFMAQ(mh, nh)                                                         \
    PRIO1();                                                                  \
    _Pragma("unroll")                                                         \
    for (int mi = 0; mi < 4; ++mi)                                            \
        _Pragma("unroll")                                                     \
        for (int ni = 0; ni < 2; ++ni)                                        \
            _Pragma("unroll")                                                 \
            for (int ks = 0; ks < 2; ++ks)                                    \
                acc[(mh)*4 + mi][(nh)*2 + ni] =                               \
                    __builtin_amdgcn_mfma_f32_16x16x32_bf16(                  \
                        aF[mh][mi][ks], bF[nh][ni][ks],                       \
                        acc[(mh)*4 + mi][(nh)*2 + ni], 0, 0, 0);              \
    PRIO0()

    // prologue: stage tile 0 halves A0,B0,A1,B1; ensure A0,B0 complete
    stageA(0, 0, 0); stageB(0, 0, 0); stageA(0, 1, 0); stageB(0, 1, 0);
    VMW(3); BAR();

    for (int T = 0; T < NT; ++T) {
        const int p = T & 1, q2 = p ^ 1;
        const bool more = (T + 1 < NT);
        // ---- ph0: reads A0,B0[T]; stage A0[T+1]; guard A1[T]; MFMA q00
#pragma unroll
        for (int j = 0; j < 4; ++j) {
            aF[0][j][0] = readA(p, 0, j, 0); aF[0][j][1] = readA(p, 0, j, 1);
        }
#pragma unroll
        for (int j = 0; j < 2; ++j) {
            bF[0][j][0] = readB(p, 0, j, 0); bF[0][j][1] = readB(p, 0, j, 1);
        }
        if (more) { stageA(q2, 0, T + 1); VMW(3); } else { VMW(2); }
        BAR();
        MFMAQ(0, 0);
        // ---- ph1: reads A1[T]; stage B0[T+1]; guard B1[T]; MFMA q10
#pragma unroll
        for (int j = 0; j < 4; ++j) {
            aF[1][j][0] = readA(p, 1, j, 0); aF[1][j][1] = readA(p, 1, j, 1);
        }
        if (more) { stageB(q2, 0, T + 1); VMW(3); } else { VMW(0); }
        BAR();
        MFMAQ(1, 0);
        // ---- ph2: reads B1[T]; stage A1,B1[T+1]; guard A0,B0[T+1];
        //           MFMA q11 + q01 (32-MFMA burst)
#pragma unroll
        for (int j = 0; j < 2; ++j) {
            bF[1][j][0] = readB(p, 1, j, 0); bF[1][j][1] = readB(p, 1, j, 1);
        }
        if (more) { stageA(q2, 1, T + 1); stageB(q2, 1, T + 1); VMW(3); }
        BAR();
        MFMAQ(1, 1);
        MFMAQ(0, 1);
    }

    // fused LSTM epilogue: acc[mi][ni] regs = f,i,o,g of unit r, col n
    const int rB = bm * 64;
    const int nB = bn * 256;
    float zc[4], zbv[4];
#pragma unroll
    for (int ni = 0; ni < 4; ++ni) {
        int n = nB + (ni >> 1) * 128 + wn * 32 + (ni & 1) * 16 + fr;
        zc[ni] = z[n]; zbv[ni] = zb[n];
    }
#pragma unroll
    for (int mi = 0; mi < 8; ++mi) {
        const int r = rB + (mi >> 2) * 32 + wm * 16 + (mi & 3) * 4 + fq;
        const float b0 = bias[r], b1 = bias[Hd + r], b2 = bias[2 * Hd + r], b3 = bias[3 * Hd + r];
        const float* crow = c_in + (size_t)r * Bsz;
        const float* hrow = h_in + (size_t)r * Bsz;
        float* hout = out + (size_t)r * Bsz;
        float* cout = out + (size_t)Hd * Bsz + (size_t)r * Bsz;
#pragma unroll
        for (int ni = 0; ni < 4; ++ni) {
            const int n = nB + (ni >> 1) * 128 + wn * 32 + (ni & 1) * 16 + fr;
            f32x4 a = acc[mi][ni];
            float co = crow[n], ho = hrow[n];
            float fg = sigm(a[0] + b0);
            float ig = sigm(a[1] + b1);
            float og = sigm(a[2] + b2);
            float gg = tanhf(a[3] + b3);
            float i_g = ig * gg;
            float nz = 1.0f - zc[ni], nzb = 1.0f - zbv[ni];
            float cn = zc[ni] * i_g + nz * nzb * co + nz * zbv[ni] * (fg * co + i_g);
            float tc2 = tanhf(cn);
            float hn = zc[ni] * og * tc2 + nz * nzb * ho + nz * zbv[ni] * og * tc2;
            hout[n] = hn; cout[n] = cn;
        }
    }

    // z-row finalize (16 blocks with bm==0 cover all 4096 columns)
    if (bm == 0 && t < 256) {
        float* outz = out + (size_t)2 * Hd * Bsz;
        int n = bn * 256 + t;
        float s = outz[n] + bias[4096];
        float zh = (s + 1.0f) * 0.5f;
        zh = fminf(fmaxf(zh, 0.0f), 1.0f);
        outz[n] = (zh > 0.5f) ? 1.0f : 0.0f;
    }
#undef MFMAQ
}

extern "C" void kernel_launch(void* const* d_in, const int* in_sizes, int n_in,
                              void* d_out, int out_size, void* d_ws, size_t ws_size,
                              hipStream_t stream) {
    (void)in_sizes; (void)n_in; (void)out_size; (void)ws_size;
    const float* c    = (const float*)d_in[0];
    const float* hb   = (const float*)d_in[1];
    const float* h    = (const float*)d_in[2];
    const float* ht   = (const float*)d_in[3];
    const float* z    = (const float*)d_in[4];
    const float* zb   = (const float*)d_in[5];
    const float* U11  = (const float*)d_in[6];
    const float* U21  = (const float*)d_in[7];
    const float* W01  = (const float*)d_in[8];
    const float* bias = (const float*)d_in[9];
    float* out = (float*)d_out;

    u16* Ab = (u16*)d_ws;                          // 25.2 MB
    u16* Bb = Ab + (size_t)4096 * Kc;              // 25.2 MB

    hipFuncSetAttribute(reinterpret_cast<const void*>(gemm_fused),
                        hipFuncAttributeMaxDynamicSharedMemorySize, 131072);

    prep_A<<<6144, 256, 0, stream>>>(U11, U21, W01, Ab, out);
    prep_B<<<dim3(128, 48), 256, 0, stream>>>(hb, ht, h, z, zb, U11, U21, W01, Bb, out);
    gemm_fused<<<256, 512, 131072, stream>>>(Ab, Bb, c, h, z, zb, bias, out);
}